// Round 22
// baseline (116.887 us; speedup 1.0000x reference)
//
#include <hip/hip_runtime.h>
#include <hip/hip_bf16.h>
#include <cstdint>

#define Hh 16
#define Dd 1024
#define HD 64
#define Bb 2
#define Ss 2048

typedef float f32x4 __attribute__((ext_vector_type(4)));
typedef __bf16 bf16x8 __attribute__((ext_vector_type(8)));

__device__ __forceinline__ unsigned short f2bf(float f) {
  union { float f; unsigned u; } v; v.f = f;
  unsigned r = (v.u + 0x7FFFu + ((v.u >> 16) & 1u)) >> 16;  // RNE, finite inputs
  return (unsigned short)r;
}

__device__ __forceinline__ void gld16(const void* g, void* l) {
  __builtin_amdgcn_global_load_lds(
      (__attribute__((address_space(1))) void*)(g),
      (__attribute__((address_space(3))) void*)(l),
      16, 0, 0);
}

// ---------------------------------------------------------------------------
// Merged prep: pack x (b<4096), transpose Wq/Wk/Wv (4096<=b<4864, 48 mats),
// transpose Wo (4864<=b<5120). One dispatch replaces three (saves 2 launch
// gaps; bodies identical to the previously verified kernels).
// ---------------------------------------------------------------------------
__global__ __launch_bounds__(256)
void prep_k(const float4* __restrict__ x, unsigned short* __restrict__ xb,
            const float* __restrict__ Wq, const float* __restrict__ Wk,
            const float* __restrict__ Wv, unsigned short* __restrict__ wqkvT,
            float qscale,
            const float* __restrict__ Wo, unsigned short* __restrict__ woT)
{
  const int b = blockIdx.x;
  if (b < 4096) {
    const int i = b * 256 + threadIdx.x;
    const float4 v = x[i];
    ushort4 o;
    o.x = f2bf(v.x); o.y = f2bf(v.y); o.z = f2bf(v.z); o.w = f2bf(v.w);
    *(ushort4*)&xb[(size_t)i * 4] = o;
    return;
  }
  __shared__ float T[64][65];
  const int tx = threadIdx.x & 63, ty = threadIdx.x >> 6;
  if (b < 4864) {
    const int rel = b - 4096;           // 0..767
    const int m = rel >> 4;             // 0..47
    const int r0 = (rel & 15) * 64;
    const float* base = (m < 16) ? Wq : (m < 32) ? Wk : Wv;
    const float scale = (m < 16) ? qscale : 1.0f;
    const float* src = base + (size_t)(m & 15) * 65536;
    unsigned short* dst = wqkvT + (size_t)m * 65536;
#pragma unroll
    for (int it = 0; it < 16; ++it) {
      const int i = ty + it * 4;
      T[i][tx] = src[(size_t)(r0 + i) * 64 + tx];
    }
    __syncthreads();
#pragma unroll
    for (int it = 0; it < 16; ++it) {
      const int jj = ty + it * 4;
      dst[(size_t)jj * 1024 + r0 + tx] = f2bf(T[tx][jj] * scale);
    }
  } else {
    const int rel = b - 4864;           // 0..255
    const int c0 = (rel & 15) * 64, r0 = (rel >> 4) * 64;
#pragma unroll
    for (int it = 0; it < 16; ++it) {
      const int i = ty + it * 4;
      T[i][tx] = Wo[(size_t)(r0 + i) * 1024 + c0 + tx];
    }
    __syncthreads();
#pragma unroll
    for (int it = 0; it < 16; ++it) {
      const int jj = ty + it * 4;
      woT[(size_t)(c0 + jj) * 1024 + r0 + tx] = f2bf(T[tx][jj]);
    }
  }
}

// ---------------------------------------------------------------------------
// Merged QKV projection: A[4096][1024] @ wqkvT[3072][1024]^T.
// r17's BEST-MEASURED variant (52.0us): 64x128 tile, BK=64, 4 waves,
// double-buffered 48KB LDS, depth-2 counted-vmcnt pipeline (compute buf[c]
// -> s_barrier -> stage t+2 -> vmcnt(6) -> s_barrier; sched_barrier pins;
// loop var cc). PLUS r19's T1 XCD chunking (FETCH -15% measured): 1D grid
// 1536, xcd=b&7 owns a 12x16 sub-grid (B 3MB + A 2MB ~ L2).
// [r20's B-direct-from-global variant REGRESSED 54->89us: B fragment loads
// exposed L2 latency inside every K-step. Reverted. Nine structural
// variants all land 50-55us -> multi-resource equilibrium; structure holds.]
// col0 < 2048 -> q/k (TRANSPOSED acc via operand swap, ushort4 [bh][s][e]);
// else v (normal acc, ushort4 V^T [bh][e][s]).
// ---------------------------------------------------------------------------
__global__ __launch_bounds__(256)
void gemm_qkv(const unsigned short* __restrict__ A,
              const unsigned short* __restrict__ Bt,
              unsigned short* __restrict__ q_out,
              unsigned short* __restrict__ k_out,
              unsigned short* __restrict__ vt_out)
{
  __shared__ unsigned short As[2][64 * 64];    // 16 KB
  __shared__ unsigned short Bs[2][128 * 64];   // 32 KB

  const int K = 1024, NT = 16;
  const int tid = threadIdx.x;
  const int w = tid >> 6, lane = tid & 63;
  const int lo = lane & 15, hi = lane >> 4;
  const int wr = w >> 1, wc = w & 1;

  // T1: XCD-chunked mapping (bijective over 24 cols x 64 rows)
  const int b = blockIdx.x;
  const int xcd = b & 7, idx = b >> 3;          // idx 0..191
  const int cx = idx % 12, cy = idx / 12;       // 12 cols x 16 rows per XCD
  const int col0 = ((xcd & 1) * 12 + cx) * 128;
  const int row0 = (((xcd >> 1) & 3) * 16 + cy) * 64;
  const bool isv = (col0 >= 2048);

  f32x4 acc[2][4] = {};

  const int sr   = lane >> 3;
  const int scol = ((lane & 7) ^ sr) * 8;
  const int swl  = (lo & 7) << 4;

// 6 loads/thread/tile (2 A + 4 B); loop var cc (NOT c — r13 capture bug)
#define QSTAGE(bi, k0)                                                   \
  _Pragma("unroll")                                                      \
  for (int cc = 0; cc < 2; ++cc)                                         \
    gld16(A + (size_t)(row0 + cc * 32 + w * 8 + sr) * K + ((k0) + scol), \
          (char*)&As[bi][0] + cc * 4096 + w * 1024);                     \
  _Pragma("unroll")                                                      \
  for (int cc = 0; cc < 4; ++cc)                                         \
    gld16(Bt + (size_t)(col0 + cc * 32 + w * 8 + sr) * K + ((k0) + scol),\
          (char*)&Bs[bi][0] + cc * 4096 + w * 1024);

  // prologue: tiles 0 and 1 in flight; wait tile 0 only (6 newest remain)
  QSTAGE(0, 0);
  QSTAGE(1, 64);
  __builtin_amdgcn_sched_barrier(0);
  asm volatile("s_waitcnt vmcnt(6)" ::: "memory");
  __builtin_amdgcn_sched_barrier(0);
  __builtin_amdgcn_s_barrier();
  __builtin_amdgcn_sched_barrier(0);

  for (int t = 0; t < NT; ++t) {
    const int c = t & 1;
#pragma unroll
    for (int ks = 0; ks < 2; ++ks) {
      bf16x8 af[2], bfr[4];
#pragma unroll
      for (int i = 0; i < 2; ++i)
        af[i] = *(const bf16x8*)((const char*)&As[c][0] +
                 (wr * 32 + i * 16 + lo) * 128 + ((ks * 64 + hi * 16) ^ swl));
#pragma unroll
      for (int j = 0; j < 4; ++j)
        bfr[j] = *(const bf16x8*)((const char*)&Bs[c][0] +
                 (wc * 64 + j * 16 + lo) * 128 + ((ks * 64 + hi * 16) ^ swl));
      __builtin_amdgcn_s_setprio(1);
      if (isv) {
#pragma unroll
        for (int i = 0; i < 2; ++i)
#pragma unroll
          for (int j = 0; j < 4; ++j)
            acc[i][j] = __builtin_amdgcn_mfma_f32_16x16x32_bf16(af[i], bfr[j], acc[i][j], 0, 0, 0);
      } else {
#pragma unroll
        for (int i = 0; i < 2; ++i)
#pragma unroll
          for (int j = 0; j < 4; ++j)
            acc[i][j] = __builtin_amdgcn_mfma_f32_16x16x32_bf16(bfr[j], af[i], acc[i][j], 0, 0, 0);
      }
      __builtin_amdgcn_s_setprio(0);
    }
    // all waves done reading buf[c]
    __builtin_amdgcn_sched_barrier(0);
    __builtin_amdgcn_s_barrier();
    __builtin_amdgcn_sched_barrier(0);
    if (t + 2 < NT) {
      QSTAGE(c, (t + 2) * 64);                           // refill freed buffer
      __builtin_amdgcn_sched_barrier(0);
      asm volatile("s_waitcnt vmcnt(6)" ::: "memory");   // t+1 landed; t+2 in flight
    } else if (t + 1 < NT) {
      asm volatile("s_waitcnt vmcnt(0)" ::: "memory");   // tail: drain tile t+1
    }
    __builtin_amdgcn_sched_barrier(0);
    __builtin_amdgcn_s_barrier();
    __builtin_amdgcn_sched_barrier(0);
  }
#undef QSTAGE

#pragma unroll
  for (int i = 0; i < 2; ++i) {
#pragma unroll
    for (int j = 0; j < 4; ++j) {
      if (isv) {
        // normal acc: lane holds 4 consecutive s at fixed e
        const int grow = row0 + wr * 32 + i * 16 + hi * 4;
        const int gcol = col0 + wc * 64 + j * 16 + lo;     // 2048..3071
        const int hd = (gcol >> 6) & 15, e = gcol & 63;
        const int bb2 = grow >> 11, s = grow & 2047;
        ushort4 pk;
        pk.x = f2bf(acc[i][j][0]); pk.y = f2bf(acc[i][j][1]);
        pk.z = f2bf(acc[i][j][2]); pk.w = f2bf(acc[i][j][3]);
        *(ushort4*)&vt_out[((size_t)(bb2 * Hh + hd) * HD + e) * Ss + s] = pk;
      } else {
        // transposed acc: lane holds 4 consecutive n at fixed row m
        const int m  = row0 + wr * 32 + i * 16 + lo;
        const int n0 = col0 + wc * 64 + j * 16 + hi * 4;
        const int p = n0 >> 10;
        const int hd = (n0 >> 6) & 15, e = n0 & 63;
        const int bb2 = m >> 11, s = m & 2047;
        unsigned short* dst = (p == 0) ? q_out : k_out;
        ushort4 pk;
        pk.x = f2bf(acc[i][j][0]); pk.y = f2bf(acc[i][j][1]);
        pk.z = f2bf(acc[i][j][2]); pk.w = f2bf(acc[i][j][3]);
        *(ushort4*)&dst[((size_t)(bb2 * Hh + hd) * Ss + s) * HD + e] = pk;
      }
    }
  }
}

// ---------------------------------------------------------------------------
// Out-projection GEMM: [4096x1024] @ woT[1024][1024]^T + bias, fp32 out.
// 64x128 tile, BK=128 two-half structure, 48KB LDS, T2 swizzle, TRANSPOSED
// acc -> float4 stores. T1: 1D grid 512, xcd=b&7 owns 8 cols x 8 rows.
// (unchanged from r19)
// ---------------------------------------------------------------------------
__global__ __launch_bounds__(256)
void gemm_out(const unsigned short* __restrict__ A,
              const unsigned short* __restrict__ Bt,
              float* __restrict__ o_out,
              const float* __restrict__ bias)
{
  __shared__ unsigned short As[2][64 * 64];    // 16 KB
  __shared__ unsigned short Bs[2][128 * 64];   // 32 KB

  const int K = 1024, Ndim = 1024;
  const int tid = threadIdx.x;
  const int w = tid >> 6, lane = tid & 63;
  const int lo = lane & 15, hi = lane >> 4;
  const int wr = w >> 1, wc = w & 1;

  const int b = blockIdx.x;
  const int xcd = b & 7, idx = b >> 3;          // idx 0..63
  const int col0 = (idx & 7) * 128;
  const int row0 = ((idx >> 3) + xcd * 8) * 64;

  f32x4 acc[2][4] = {};

  const int sr   = lane >> 3;
  const int scol = ((lane & 7) ^ sr) * 8;
  const int swl  = (lo & 7) << 4;

  for (int t = 0; t < 8; ++t) {
    const int k0 = t * 128;
#pragma unroll
    for (int h = 0; h < 2; ++h) {
      const int kh = k0 + h * 64;
#pragma unroll
      for (int cc = 0; cc < 2; ++cc)
        gld16(A + (size_t)(row0 + cc * 32 + w * 8 + sr) * K + (kh + scol),
              (char*)&As[h][0] + cc * 4096 + w * 1024);
#pragma unroll
      for (int cc = 0; cc < 4; ++cc)
        gld16(Bt + (size_t)(col0 + cc * 32 + w * 8 + sr) * K + (kh + scol),
              (char*)&Bs[h][0] + cc * 4096 + w * 1024);
    }
    __syncthreads();
#pragma unroll
    for (int h = 0; h < 2; ++h) {
#pragma unroll
      for (int ks = 0; ks < 2; ++ks) {
        bf16x8 af[2], bfr[4];
#pragma unroll
        for (int i = 0; i < 2; ++i)
          af[i] = *(const bf16x8*)((const char*)&As[h][0] +
                   (wr * 32 + i * 16 + lo) * 128 + ((ks * 64 + hi * 16) ^ swl));
#pragma unroll
        for (int j = 0; j < 4; ++j)
          bfr[j] = *(const bf16x8*)((const char*)&Bs[h][0] +
                   (wc * 64 + j * 16 + lo) * 128 + ((ks * 64 + hi * 16) ^ swl));
        __builtin_amdgcn_s_setprio(1);
#pragma unroll
        for (int i = 0; i < 2; ++i)
#pragma unroll
          for (int j = 0; j < 4; ++j)
            acc[i][j] = __builtin_amdgcn_mfma_f32_16x16x32_bf16(bfr[j], af[i], acc[i][j], 0, 0, 0);
        __builtin_amdgcn_s_setprio(0);
      }
    }
    __syncthreads();
  }

#pragma unroll
  for (int i = 0; i < 2; ++i) {
#pragma unroll
    for (int j = 0; j < 4; ++j) {
      const int m  = row0 + wr * 32 + i * 16 + lo;
      const int n0 = col0 + wc * 64 + j * 16 + hi * 4;
      const float4 bv = *(const float4*)&bias[n0];
      float4 o;
      o.x = acc[i][j][0] + bv.x; o.y = acc[i][j][1] + bv.y;
      o.z = acc[i][j][2] + bv.z; o.w = acc[i][j][3] + bv.w;
      *(float4*)&o_out[(size_t)m * Ndim + n0] = o;
    }
  }
}

// ---------------------------------------------------------------------------
// Flash attention, causal, swapped-QK^T in-register-P, 4 waves x 16 q-rows.
// grid (B*H, 32), balanced qt LUT. (unchanged)
// ---------------------------------------------------------------------------
__global__ __launch_bounds__(256)
void attn_fwd(const unsigned short* __restrict__ qb,
              const unsigned short* __restrict__ kb,
              const unsigned short* __restrict__ vtb,
              unsigned short* __restrict__ ob)
{
  __shared__ unsigned short Ks[2][64 * 64];
  __shared__ unsigned short Vs[2][64 * 64];

  const int y = blockIdx.y;
  const int y0 = y & 7;
  const int k8 = y >> 3;
  const int qt = (k8 == 0) ? (31 - y0) : (k8 == 1) ? (16 + y0)
               : (k8 == 2) ? (15 - y0) : y0;
  const int bh = blockIdx.x;
  const int bb2 = bh >> 4;
  const int hd = bh & 15;

  const unsigned short* Q  = qb  + (size_t)bh * Ss * HD;
  const unsigned short* Kg = kb  + (size_t)bh * Ss * HD;
  const unsigned short* Vt = vtb + (size_t)bh * HD * Ss;

  const int tid = threadIdx.x;
  const int w = tid >> 6, lane = tid & 63;
  const int lo = lane & 15, hi = lane >> 4;
  const int qrow0 = qt * 64 + w * 16;

  const int sr   = lane >> 3;
  const int scol = ((lane & 7) ^ sr) * 8;
  int prow[2];
#pragma unroll
  for (int c = 0; c < 2; ++c) {
    const int L = c * 4 + w;
    prow[c] = (L >> 2) * 32 + ((L & 1) * 2 + (sr >> 2)) * 8 + ((L >> 1) & 1) * 4 + (sr & 3);
  }

#define STAGE(bi, kv)                                                     \
  _Pragma("unroll")                                                       \
  for (int c = 0; c < 2; ++c) {                                           \
    const int L = c * 4 + w;                                              \
    gld16(Kg + (size_t)((kv) + prow[c]) * HD + scol,                      \
          (char*)&Ks[bi][0] + L * 1024);                                  \
    gld16(Vt + (size_t)(L * 8 + sr) * Ss + (kv) + scol,                   \
          (char*)&Vs[bi][0] + L * 1024);                                  \
  }

  const int swl = (lo & 7) << 4;

  bf16x8 vones;
#pragma unroll
  for (int j = 0; j < 8; ++j) vones[j] = (__bf16)1.0f;

  bf16x8 qf[2];
#pragma unroll
  for (int ks = 0; ks < 2; ++ks)
    qf[ks] = *(const bf16x8*)&Q[(size_t)(qrow0 + lo) * HD + ks * 32 + hi * 8];

  f32x4 oacc[4] = {};
  float m2s = -INFINITY;
  float l2[4];
#pragma unroll
  for (int r = 0; r < 4; ++r) l2[r] = 0.f;

  const int ntiles = qt + 1;

  STAGE(0, 0);
  __syncthreads();

  int cur = 0;
  for (int t = 0; t < ntiles; ++t) {
    if (t + 1 < ntiles) { STAGE(cur ^ 1, (t + 1) * 64); }

    f32x4 sacc[4] = {};
    __builtin_amdgcn_s_setprio(1);
#pragma unroll
    for (int ks = 0; ks < 2; ++ks) {
      bf16x8 kf[4];
#pragma unroll
      for (int nj = 0; nj < 4; ++nj)
        kf[nj] = *(const bf16x8*)((const char*)&Ks[cur][0] +
                 (nj * 16 + lo) * 128 + ((ks * 64 + hi * 16) ^ swl));
#pragma unroll
      for (int nj = 0; nj < 4; ++nj)
        sacc[nj] = __builtin_amdgcn_mfma_f32_16x16x32_bf16(kf[nj], qf[ks], sacc[nj], 0, 0, 0);
    }
    __builtin_amdgcn_s_setprio(0);

    if (t == qt) {
      const int qr = w * 16 + lo;
#pragma unroll
      for (int nj = 0; nj < 4; ++nj) {
        const int kb0 = (nj >> 1) * 32 + (nj & 1) * 4 + hi * 8;
#pragma unroll
        for (int r = 0; r < 4; ++r)
          if (kb0 + r > qr) sacc[nj][r] = -INFINITY;
      }
    }

    float a0 = fmaxf(fmaxf(sacc[0][0], sacc[0][1]), fmaxf(sacc[0][2], sacc[0][3]));
    float a1 = fmaxf(fmaxf(sacc[1][0], sacc[1][1]), fmaxf(sacc[1][2], sacc[1][3]));
    float a2 = fmaxf(fmaxf(sacc[2][0], sacc[2][1]), fmaxf(sacc[2][2], sacc[2][3]));
    float a3 = fmaxf(fmaxf(sacc[3][0], sacc[3][1]), fmaxf(sacc[3][2], sacc[3][3]));
    const float lmax = fmaxf(fmaxf(a0, a1), fmaxf(a2, a3));
    if (!__all(lmax - m2s <= 8.0f)) {
      float rm = lmax;
      rm = fmaxf(rm, __shfl_xor(rm, 16, 64));
      rm = fmaxf(rm, __shfl_xor(rm, 32, 64));
      const float mn = fmaxf(m2s, rm);
      const float rcs = __builtin_amdgcn_exp2f(m2s - mn);
      m2s = mn;
#pragma unroll
      for (int r = 0; r < 4; ++r) {
        const float rc = __shfl(rcs, hi * 4 + r, 64);
        l2[r] *= rc;
#pragma unroll
        for (int nj = 0; nj < 4; ++nj)
          oacc[nj][r] *= rc;
      }
    }

    bf16x8 pa[2];
#pragma unroll
    for (int ks = 0; ks < 2; ++ks)
#pragma unroll
      for (int j = 0; j < 4; ++j) {
        pa[ks][j]     = (__bf16)__builtin_amdgcn_exp2f(sacc[2 * ks][j]     - m2s);
        pa[ks][4 + j] = (__bf16)__builtin_amdgcn_exp2f(sacc[2 * ks + 1][j] - m2s);
      }

    f32x4 osum = {};
    __builtin_amdgcn_s_setprio(1);
#pragma unroll
    for (int ks = 0; ks < 2; ++ks) {
      bf16x8 vf[4];
#pragma unroll
      for (int nj = 0; nj < 4; ++nj)
        vf[nj] = *(const bf16x8*)((const char*)&Vs[cur][0] +
                 (nj * 16 + lo) * 128 + ((ks * 64 + hi * 16) ^ swl));
#pragma unroll
      for (int nj = 0; nj < 4; ++nj)
        oacc[nj] = __builtin_amdgcn_mfma_f32_16x16x32_bf16(pa[ks], vf[nj], oacc[nj], 0, 0, 0);
      osum = __builtin_amdgcn_mfma_f32_16x16x32_bf16(pa[ks], vones, osum, 0, 0, 0);
    }
    __builtin_amdgcn_s_setprio(0);
#pragma unroll
    for (int r = 0; r < 4; ++r)
      l2[r] += osum[r];

    __syncthreads();
    cur ^= 1;
  }
#undef STAGE

#pragma unroll
  for (int r = 0; r < 4; ++r) {
    const int s = qrow0 + hi * 4 + r;
    const float il = 1.0f / l2[r];
    const size_t base = ((size_t)bb2 * Ss + s) * Dd + hd * HD;
#pragma unroll
    for (int nj = 0; nj < 4; ++nj)
      ob[base + nj * 16 + lo] = f2bf(oacc[nj][r] * il);
  }
}

// ---------------------------------------------------------------------------
extern "C" void kernel_launch(void* const* d_in, const int* in_sizes, int n_in,
                              void* d_out, int out_size, void* d_ws, size_t ws_size,
                              hipStream_t stream)
{
  const float* x  = (const float*)d_in[0];
  const float* Wq = (const float*)d_in[1];
  const float* Wk = (const float*)d_in[2];
  const float* Wv = (const float*)d_in[3];
  const float* Wo = (const float*)d_in[4];
  const float* bo = (const float*)d_in[5];
  float* out = (float*)d_out;

  char* ws = (char*)d_ws;
  unsigned short* xb    = (unsigned short*)(ws);              //  8,388,608 B
  unsigned short* wqkvT = (unsigned short*)(ws + 8388608);    //  6,291,456 B
  unsigned short* woT   = (unsigned short*)(ws + 14680064);   //  2,097,152 B
  unsigned short* qb    = (unsigned short*)(ws + 16777216);   //  8,388,608 B
  unsigned short* kb    = (unsigned short*)(ws + 25165824);   //  8,388,608 B
  unsigned short* vtb   = (unsigned short*)(ws + 33554432);   //  8,388,608 B
  unsigned short* ob    = (unsigned short*)(ws + 41943040);   //  8,388,608 B (end 48 MiB)

  // merged prep: pack x + transpose Wq/Wk/Wv (Wq carries 1/8*log2(e)) + Wo
  prep_k<<<dim3(5120), 256, 0, stream>>>((const float4*)x, xb,
                                         Wq, Wk, Wv, wqkvT,
                                         0.18033688011112042f, Wo, woT);

  // merged QKV projection (64x128 depth-2 counted-vmcnt + T1 chunking)
  gemm_qkv<<<dim3(1536), 256, 0, stream>>>(xb, wqkvT, qb, kb, vtb);
  // attention (4 waves x 16 q-rows per 64-row q-tile; balanced qt LUT)
  attn_fwd<<<dim3(32, 32), 256, 0, stream>>>(qb, kb, vtb, ob);
  // out-proj: [4096x1024] @ [1024x1024] + bo (64x128, BK=128, T1 chunking)
  gemm_out<<<dim3(512), 256, 0, stream>>>(ob, woT, out, bo);
}

// Round 23
// 116.303 us; speedup vs baseline: 1.0050x; 1.0050x over previous
//
#include <hip/hip_runtime.h>
#include <hip/hip_bf16.h>
#include <cstdint>

#define Hh 16
#define Dd 1024
#define HD 64
#define Bb 2
#define Ss 2048

typedef float f32x4 __attribute__((ext_vector_type(4)));
typedef __bf16 bf16x8 __attribute__((ext_vector_type(8)));

__device__ __forceinline__ unsigned short f2bf(float f) {
  union { float f; unsigned u; } v; v.f = f;
  unsigned r = (v.u + 0x7FFFu + ((v.u >> 16) & 1u)) >> 16;  // RNE, finite inputs
  return (unsigned short)r;
}

__device__ __forceinline__ void gld16(const void* g, void* l) {
  __builtin_amdgcn_global_load_lds(
      (__attribute__((address_space(1))) void*)(g),
      (__attribute__((address_space(3))) void*)(l),
      16, 0, 0);
}

// ---------------------------------------------------------------------------
// Merged prep: pack x (b<4096), transpose Wq/Wk/Wv (4096<=b<4864, 48 mats),
// transpose Wo (4864<=b<5120). One dispatch replaces three (saves 2 launch
// gaps; bodies identical to the previously verified kernels).
// ---------------------------------------------------------------------------
__global__ __launch_bounds__(256)
void prep_k(const float4* __restrict__ x, unsigned short* __restrict__ xb,
            const float* __restrict__ Wq, const float* __restrict__ Wk,
            const float* __restrict__ Wv, unsigned short* __restrict__ wqkvT,
            float qscale,
            const float* __restrict__ Wo, unsigned short* __restrict__ woT)
{
  const int b = blockIdx.x;
  if (b < 4096) {
    const int i = b * 256 + threadIdx.x;
    const float4 v = x[i];
    ushort4 o;
    o.x = f2bf(v.x); o.y = f2bf(v.y); o.z = f2bf(v.z); o.w = f2bf(v.w);
    *(ushort4*)&xb[(size_t)i * 4] = o;
    return;
  }
  __shared__ float T[64][65];
  const int tx = threadIdx.x & 63, ty = threadIdx.x >> 6;
  if (b < 4864) {
    const int rel = b - 4096;           // 0..767
    const int m = rel >> 4;             // 0..47
    const int r0 = (rel & 15) * 64;
    const float* base = (m < 16) ? Wq : (m < 32) ? Wk : Wv;
    const float scale = (m < 16) ? qscale : 1.0f;
    const float* src = base + (size_t)(m & 15) * 65536;
    unsigned short* dst = wqkvT + (size_t)m * 65536;
#pragma unroll
    for (int it = 0; it < 16; ++it) {
      const int i = ty + it * 4;
      T[i][tx] = src[(size_t)(r0 + i) * 64 + tx];
    }
    __syncthreads();
#pragma unroll
    for (int it = 0; it < 16; ++it) {
      const int jj = ty + it * 4;
      dst[(size_t)jj * 1024 + r0 + tx] = f2bf(T[tx][jj] * scale);
    }
  } else {
    const int rel = b - 4864;           // 0..255
    const int c0 = (rel & 15) * 64, r0 = (rel >> 4) * 64;
#pragma unroll
    for (int it = 0; it < 16; ++it) {
      const int i = ty + it * 4;
      T[i][tx] = Wo[(size_t)(r0 + i) * 1024 + c0 + tx];
    }
    __syncthreads();
#pragma unroll
    for (int it = 0; it < 16; ++it) {
      const int jj = ty + it * 4;
      woT[(size_t)(c0 + jj) * 1024 + r0 + tx] = f2bf(T[tx][jj]);
    }
  }
}

// ---------------------------------------------------------------------------
// Merged QKV projection: A[4096][1024] @ wqkvT[3072][1024]^T.
// r17's BEST-MEASURED variant (52.0us): 64x128 tile, BK=64, 4 waves,
// double-buffered 48KB LDS, depth-2 counted-vmcnt pipeline (compute buf[c]
// -> s_barrier -> stage t+2 -> vmcnt(6) -> s_barrier; sched_barrier pins;
// loop var cc). PLUS r19's T1 XCD chunking (FETCH -15% measured): 1D grid
// 1536, xcd=b&7 owns a 12x16 sub-grid (B 3MB + A 2MB ~ L2).
// [r20's B-direct-from-global variant REGRESSED 54->89us: B fragment loads
// exposed L2 latency inside every K-step. Reverted. Nine structural
// variants all land 50-55us -> multi-resource equilibrium; structure holds.]
// col0 < 2048 -> q/k (TRANSPOSED acc via operand swap, ushort4 [bh][s][e]);
// else v (normal acc, ushort4 V^T [bh][e][s]).
// ---------------------------------------------------------------------------
__global__ __launch_bounds__(256)
void gemm_qkv(const unsigned short* __restrict__ A,
              const unsigned short* __restrict__ Bt,
              unsigned short* __restrict__ q_out,
              unsigned short* __restrict__ k_out,
              unsigned short* __restrict__ vt_out)
{
  __shared__ unsigned short As[2][64 * 64];    // 16 KB
  __shared__ unsigned short Bs[2][128 * 64];   // 32 KB

  const int K = 1024, NT = 16;
  const int tid = threadIdx.x;
  const int w = tid >> 6, lane = tid & 63;
  const int lo = lane & 15, hi = lane >> 4;
  const int wr = w >> 1, wc = w & 1;

  // T1: XCD-chunked mapping (bijective over 24 cols x 64 rows)
  const int b = blockIdx.x;
  const int xcd = b & 7, idx = b >> 3;          // idx 0..191
  const int cx = idx % 12, cy = idx / 12;       // 12 cols x 16 rows per XCD
  const int col0 = ((xcd & 1) * 12 + cx) * 128;
  const int row0 = (((xcd >> 1) & 3) * 16 + cy) * 64;
  const bool isv = (col0 >= 2048);

  f32x4 acc[2][4] = {};

  const int sr   = lane >> 3;
  const int scol = ((lane & 7) ^ sr) * 8;
  const int swl  = (lo & 7) << 4;

// 6 loads/thread/tile (2 A + 4 B); loop var cc (NOT c — r13 capture bug)
#define QSTAGE(bi, k0)                                                   \
  _Pragma("unroll")                                                      \
  for (int cc = 0; cc < 2; ++cc)                                         \
    gld16(A + (size_t)(row0 + cc * 32 + w * 8 + sr) * K + ((k0) + scol), \
          (char*)&As[bi][0] + cc * 4096 + w * 1024);                     \
  _Pragma("unroll")                                                      \
  for (int cc = 0; cc < 4; ++cc)                                         \
    gld16(Bt + (size_t)(col0 + cc * 32 + w * 8 + sr) * K + ((k0) + scol),\
          (char*)&Bs[bi][0] + cc * 4096 + w * 1024);

  // prologue: tiles 0 and 1 in flight; wait tile 0 only (6 newest remain)
  QSTAGE(0, 0);
  QSTAGE(1, 64);
  __builtin_amdgcn_sched_barrier(0);
  asm volatile("s_waitcnt vmcnt(6)" ::: "memory");
  __builtin_amdgcn_sched_barrier(0);
  __builtin_amdgcn_s_barrier();
  __builtin_amdgcn_sched_barrier(0);

  for (int t = 0; t < NT; ++t) {
    const int c = t & 1;
#pragma unroll
    for (int ks = 0; ks < 2; ++ks) {
      bf16x8 af[2], bfr[4];
#pragma unroll
      for (int i = 0; i < 2; ++i)
        af[i] = *(const bf16x8*)((const char*)&As[c][0] +
                 (wr * 32 + i * 16 + lo) * 128 + ((ks * 64 + hi * 16) ^ swl));
#pragma unroll
      for (int j = 0; j < 4; ++j)
        bfr[j] = *(const bf16x8*)((const char*)&Bs[c][0] +
                 (wc * 64 + j * 16 + lo) * 128 + ((ks * 64 + hi * 16) ^ swl));
      __builtin_amdgcn_s_setprio(1);
      if (isv) {
#pragma unroll
        for (int i = 0; i < 2; ++i)
#pragma unroll
          for (int j = 0; j < 4; ++j)
            acc[i][j] = __builtin_amdgcn_mfma_f32_16x16x32_bf16(af[i], bfr[j], acc[i][j], 0, 0, 0);
      } else {
#pragma unroll
        for (int i = 0; i < 2; ++i)
#pragma unroll
          for (int j = 0; j < 4; ++j)
            acc[i][j] = __builtin_amdgcn_mfma_f32_16x16x32_bf16(bfr[j], af[i], acc[i][j], 0, 0, 0);
      }
      __builtin_amdgcn_s_setprio(0);
    }
    // all waves done reading buf[c]
    __builtin_amdgcn_sched_barrier(0);
    __builtin_amdgcn_s_barrier();
    __builtin_amdgcn_sched_barrier(0);
    if (t + 2 < NT) {
      QSTAGE(c, (t + 2) * 64);                           // refill freed buffer
      __builtin_amdgcn_sched_barrier(0);
      asm volatile("s_waitcnt vmcnt(6)" ::: "memory");   // t+1 landed; t+2 in flight
    } else if (t + 1 < NT) {
      asm volatile("s_waitcnt vmcnt(0)" ::: "memory");   // tail: drain tile t+1
    }
    __builtin_amdgcn_sched_barrier(0);
    __builtin_amdgcn_s_barrier();
    __builtin_amdgcn_sched_barrier(0);
  }
#undef QSTAGE

#pragma unroll
  for (int i = 0; i < 2; ++i) {
#pragma unroll
    for (int j = 0; j < 4; ++j) {
      if (isv) {
        // normal acc: lane holds 4 consecutive s at fixed e
        const int grow = row0 + wr * 32 + i * 16 + hi * 4;
        const int gcol = col0 + wc * 64 + j * 16 + lo;     // 2048..3071
        const int hd = (gcol >> 6) & 15, e = gcol & 63;
        const int bb2 = grow >> 11, s = grow & 2047;
        ushort4 pk;
        pk.x = f2bf(acc[i][j][0]); pk.y = f2bf(acc[i][j][1]);
        pk.z = f2bf(acc[i][j][2]); pk.w = f2bf(acc[i][j][3]);
        *(ushort4*)&vt_out[((size_t)(bb2 * Hh + hd) * HD + e) * Ss + s] = pk;
      } else {
        // transposed acc: lane holds 4 consecutive n at fixed row m
        const int m  = row0 + wr * 32 + i * 16 + lo;
        const int n0 = col0 + wc * 64 + j * 16 + hi * 4;
        const int p = n0 >> 10;
        const int hd = (n0 >> 6) & 15, e = n0 & 63;
        const int bb2 = m >> 11, s = m & 2047;
        unsigned short* dst = (p == 0) ? q_out : k_out;
        ushort4 pk;
        pk.x = f2bf(acc[i][j][0]); pk.y = f2bf(acc[i][j][1]);
        pk.z = f2bf(acc[i][j][2]); pk.w = f2bf(acc[i][j][3]);
        *(ushort4*)&dst[((size_t)(bb2 * Hh + hd) * Ss + s) * HD + e] = pk;
      }
    }
  }
}

// ---------------------------------------------------------------------------
// Out-projection GEMM: [4096x1024] @ woT[1024][1024]^T + bias, fp32 out.
// 64x128 tile, BK=128 two-half structure, 48KB LDS, T2 swizzle, TRANSPOSED
// acc -> float4 stores. T1: 1D grid 512, xcd=b&7 owns 8 cols x 8 rows.
// (unchanged from r19)
// ---------------------------------------------------------------------------
__global__ __launch_bounds__(256)
void gemm_out(const unsigned short* __restrict__ A,
              const unsigned short* __restrict__ Bt,
              float* __restrict__ o_out,
              const float* __restrict__ bias)
{
  __shared__ unsigned short As[2][64 * 64];    // 16 KB
  __shared__ unsigned short Bs[2][128 * 64];   // 32 KB

  const int K = 1024, Ndim = 1024;
  const int tid = threadIdx.x;
  const int w = tid >> 6, lane = tid & 63;
  const int lo = lane & 15, hi = lane >> 4;
  const int wr = w >> 1, wc = w & 1;

  const int b = blockIdx.x;
  const int xcd = b & 7, idx = b >> 3;          // idx 0..63
  const int col0 = (idx & 7) * 128;
  const int row0 = ((idx >> 3) + xcd * 8) * 64;

  f32x4 acc[2][4] = {};

  const int sr   = lane >> 3;
  const int scol = ((lane & 7) ^ sr) * 8;
  const int swl  = (lo & 7) << 4;

  for (int t = 0; t < 8; ++t) {
    const int k0 = t * 128;
#pragma unroll
    for (int h = 0; h < 2; ++h) {
      const int kh = k0 + h * 64;
#pragma unroll
      for (int cc = 0; cc < 2; ++cc)
        gld16(A + (size_t)(row0 + cc * 32 + w * 8 + sr) * K + (kh + scol),
              (char*)&As[h][0] + cc * 4096 + w * 1024);
#pragma unroll
      for (int cc = 0; cc < 4; ++cc)
        gld16(Bt + (size_t)(col0 + cc * 32 + w * 8 + sr) * K + (kh + scol),
              (char*)&Bs[h][0] + cc * 4096 + w * 1024);
    }
    __syncthreads();
#pragma unroll
    for (int h = 0; h < 2; ++h) {
#pragma unroll
      for (int ks = 0; ks < 2; ++ks) {
        bf16x8 af[2], bfr[4];
#pragma unroll
        for (int i = 0; i < 2; ++i)
          af[i] = *(const bf16x8*)((const char*)&As[h][0] +
                   (wr * 32 + i * 16 + lo) * 128 + ((ks * 64 + hi * 16) ^ swl));
#pragma unroll
        for (int j = 0; j < 4; ++j)
          bfr[j] = *(const bf16x8*)((const char*)&Bs[h][0] +
                   (wc * 64 + j * 16 + lo) * 128 + ((ks * 64 + hi * 16) ^ swl));
        __builtin_amdgcn_s_setprio(1);
#pragma unroll
        for (int i = 0; i < 2; ++i)
#pragma unroll
          for (int j = 0; j < 4; ++j)
            acc[i][j] = __builtin_amdgcn_mfma_f32_16x16x32_bf16(bfr[j], af[i], acc[i][j], 0, 0, 0);
        __builtin_amdgcn_s_setprio(0);
      }
    }
    __syncthreads();
  }

#pragma unroll
  for (int i = 0; i < 2; ++i) {
#pragma unroll
    for (int j = 0; j < 4; ++j) {
      const int m  = row0 + wr * 32 + i * 16 + lo;
      const int n0 = col0 + wc * 64 + j * 16 + hi * 4;
      const float4 bv = *(const float4*)&bias[n0];
      float4 o;
      o.x = acc[i][j][0] + bv.x; o.y = acc[i][j][1] + bv.y;
      o.z = acc[i][j][2] + bv.z; o.w = acc[i][j][3] + bv.w;
      *(float4*)&o_out[(size_t)m * Ndim + n0] = o;
    }
  }
}

// ---------------------------------------------------------------------------
// Flash attention, causal, swapped-QK^T in-register-P, 4 waves x 16 q-rows.
// grid (B*H, 32), balanced qt LUT. (unchanged)
// ---------------------------------------------------------------------------
__global__ __launch_bounds__(256)
void attn_fwd(const unsigned short* __restrict__ qb,
              const unsigned short* __restrict__ kb,
              const unsigned short* __restrict__ vtb,
              unsigned short* __restrict__ ob)
{
  __shared__ unsigned short Ks[2][64 * 64];
  __shared__ unsigned short Vs[2][64 * 64];

  const int y = blockIdx.y;
  const int y0 = y & 7;
  const int k8 = y >> 3;
  const int qt = (k8 == 0) ? (31 - y0) : (k8 == 1) ? (16 + y0)
               : (k8 == 2) ? (15 - y0) : y0;
  const int bh = blockIdx.x;
  const int bb2 = bh >> 4;
  const int hd = bh & 15;

  const unsigned short* Q  = qb  + (size_t)bh * Ss * HD;
  const unsigned short* Kg = kb  + (size_t)bh * Ss * HD;
  const unsigned short* Vt = vtb + (size_t)bh * HD * Ss;

  const int tid = threadIdx.x;
  const int w = tid >> 6, lane = tid & 63;
  const int lo = lane & 15, hi = lane >> 4;
  const int qrow0 = qt * 64 + w * 16;

  const int sr   = lane >> 3;
  const int scol = ((lane & 7) ^ sr) * 8;
  int prow[2];
#pragma unroll
  for (int c = 0; c < 2; ++c) {
    const int L = c * 4 + w;
    prow[c] = (L >> 2) * 32 + ((L & 1) * 2 + (sr >> 2)) * 8 + ((L >> 1) & 1) * 4 + (sr & 3);
  }

#define STAGE(bi, kv)                                                     \
  _Pragma("unroll")                                                       \
  for (int c = 0; c < 2; ++c) {                                           \
    const int L = c * 4 + w;                                              \
    gld16(Kg + (size_t)((kv) + prow[c]) * HD + scol,                      \
          (char*)&Ks[bi][0] + L * 1024);                                  \
    gld16(Vt + (size_t)(L * 8 + sr) * Ss + (kv) + scol,                   \
          (char*)&Vs[bi][0] + L * 1024);                                  \
  }

  const int swl = (lo & 7) << 4;

  bf16x8 vones;
#pragma unroll
  for (int j = 0; j < 8; ++j) vones[j] = (__bf16)1.0f;

  bf16x8 qf[2];
#pragma unroll
  for (int ks = 0; ks < 2; ++ks)
    qf[ks] = *(const bf16x8*)&Q[(size_t)(qrow0 + lo) * HD + ks * 32 + hi * 8];

  f32x4 oacc[4] = {};
  float m2s = -INFINITY;
  float l2[4];
#pragma unroll
  for (int r = 0; r < 4; ++r) l2[r] = 0.f;

  const int ntiles = qt + 1;

  STAGE(0, 0);
  __syncthreads();

  int cur = 0;
  for (int t = 0; t < ntiles; ++t) {
    if (t + 1 < ntiles) { STAGE(cur ^ 1, (t + 1) * 64); }

    f32x4 sacc[4] = {};
    __builtin_amdgcn_s_setprio(1);
#pragma unroll
    for (int ks = 0; ks < 2; ++ks) {
      bf16x8 kf[4];
#pragma unroll
      for (int nj = 0; nj < 4; ++nj)
        kf[nj] = *(const bf16x8*)((const char*)&Ks[cur][0] +
                 (nj * 16 + lo) * 128 + ((ks * 64 + hi * 16) ^ swl));
#pragma unroll
      for (int nj = 0; nj < 4; ++nj)
        sacc[nj] = __builtin_amdgcn_mfma_f32_16x16x32_bf16(kf[nj], qf[ks], sacc[nj], 0, 0, 0);
    }
    __builtin_amdgcn_s_setprio(0);

    if (t == qt) {
      const int qr = w * 16 + lo;
#pragma unroll
      for (int nj = 0; nj < 4; ++nj) {
        const int kb0 = (nj >> 1) * 32 + (nj & 1) * 4 + hi * 8;
#pragma unroll
        for (int r = 0; r < 4; ++r)
          if (kb0 + r > qr) sacc[nj][r] = -INFINITY;
      }
    }

    float a0 = fmaxf(fmaxf(sacc[0][0], sacc[0][1]), fmaxf(sacc[0][2], sacc[0][3]));
    float a1 = fmaxf(fmaxf(sacc[1][0], sacc[1][1]), fmaxf(sacc[1][2], sacc[1][3]));
    float a2 = fmaxf(fmaxf(sacc[2][0], sacc[2][1]), fmaxf(sacc[2][2], sacc[2][3]));
    float a3 = fmaxf(fmaxf(sacc[3][0], sacc[3][1]), fmaxf(sacc[3][2], sacc[3][3]));
    const float lmax = fmaxf(fmaxf(a0, a1), fmaxf(a2, a3));
    if (!__all(lmax - m2s <= 8.0f)) {
      float rm = lmax;
      rm = fmaxf(rm, __shfl_xor(rm, 16, 64));
      rm = fmaxf(rm, __shfl_xor(rm, 32, 64));
      const float mn = fmaxf(m2s, rm);
      const float rcs = __builtin_amdgcn_exp2f(m2s - mn);
      m2s = mn;
#pragma unroll
      for (int r = 0; r < 4; ++r) {
        const float rc = __shfl(rcs, hi * 4 + r, 64);
        l2[r] *= rc;
#pragma unroll
        for (int nj = 0; nj < 4; ++nj)
          oacc[nj][r] *= rc;
      }
    }

    bf16x8 pa[2];
#pragma unroll
    for (int ks = 0; ks < 2; ++ks)
#pragma unroll
      for (int j = 0; j < 4; ++j) {
        pa[ks][j]     = (__bf16)__builtin_amdgcn_exp2f(sacc[2 * ks][j]     - m2s);
        pa[ks][4 + j] = (__bf16)__builtin_amdgcn_exp2f(sacc[2 * ks + 1][j] - m2s);
      }

    f32x4 osum = {};
    __builtin_amdgcn_s_setprio(1);
#pragma unroll
    for (int ks = 0; ks < 2; ++ks) {
      bf16x8 vf[4];
#pragma unroll
      for (int nj = 0; nj < 4; ++nj)
        vf[nj] = *(const bf16x8*)((const char*)&Vs[cur][0] +
                 (nj * 16 + lo) * 128 + ((ks * 64 + hi * 16) ^ swl));
#pragma unroll
      for (int nj = 0; nj < 4; ++nj)
        oacc[nj] = __builtin_amdgcn_mfma_f32_16x16x32_bf16(pa[ks], vf[nj], oacc[nj], 0, 0, 0);
      osum = __builtin_amdgcn_mfma_f32_16x16x32_bf16(pa[ks], vones, osum, 0, 0, 0);
    }
    __builtin_amdgcn_s_setprio(0);
#pragma unroll
    for (int r = 0; r < 4; ++r)
      l2[r] += osum[r];

    __syncthreads();
    cur ^= 1;
  }
#undef STAGE

#pragma unroll
  for (int r = 0; r < 4; ++r) {
    const int s = qrow0 + hi * 4 + r;
    const float il = 1.0f / l2[r];
    const size_t base = ((size_t)bb2 * Ss + s) * Dd + hd * HD;
#pragma unroll
    for (int nj = 0; nj < 4; ++nj)
      ob[base + nj * 16 + lo] = f2bf(oacc[nj][r] * il);
  }
}

// ---------------------------------------------------------------------------
extern "C" void kernel_launch(void* const* d_in, const int* in_sizes, int n_in,
                              void* d_out, int out_size, void* d_ws, size_t ws_size,
                              hipStream_t stream)
{
  const float* x  = (const float*)d_in[0];
  const float* Wq = (const float*)d_in[1];
  const float* Wk = (const float*)d_in[2];
  const float* Wv = (const float*)d_in[3];
  const float* Wo = (const float*)d_in[4];
  const float* bo = (const float*)d_in[5];
  float* out = (float*)d_out;

  char* ws = (char*)d_ws;
  unsigned short* xb    = (unsigned short*)(ws);              //  8,388,608 B
  unsigned short* wqkvT = (unsigned short*)(ws + 8388608);    //  6,291,456 B
  unsigned short* woT   = (unsigned short*)(ws + 14680064);   //  2,097,152 B
  unsigned short* qb    = (unsigned short*)(ws + 16777216);   //  8,388,608 B
  unsigned short* kb    = (unsigned short*)(ws + 25165824);   //  8,388,608 B
  unsigned short* vtb   = (unsigned short*)(ws + 33554432);   //  8,388,608 B
  unsigned short* ob    = (unsigned short*)(ws + 41943040);   //  8,388,608 B (end 48 MiB)

  // merged prep: pack x + transpose Wq/Wk/Wv (Wq carries 1/8*log2(e)) + Wo
  prep_k<<<dim3(5120), 256, 0, stream>>>((const float4*)x, xb,
                                         Wq, Wk, Wv, wqkvT,
                                         0.18033688011112042f, Wo, woT);

  // merged QKV projection (64x128 depth-2 counted-vmcnt + T1 chunking)
  gemm_qkv<<<dim3(1536), 256, 0, stream>>>(xb, wqkvT, qb, kb, vtb);
  // attention (4 waves x 16 q-rows per 64-row q-tile; balanced qt LUT)
  attn_fwd<<<dim3(32, 32), 256, 0, stream>>>(qb, kb, vtb, ob);
  // out-proj: [4096x1024] @ [1024x1024] + bo (64x128, BK=128, T1 chunking)
  gemm_out<<<dim3(512), 256, 0, stream>>>(ob, woT, out, bo);
}